// Round 7
// baseline (204.758 us; speedup 1.0000x reference)
//
#include <hip/hip_runtime.h>

// ScaledDotProductAttention b=2,h=16,L=2048,d=64 — round 7.
// vs round 6: fused 2-way K-split. 512-thread blocks; waves 0-3 do keys
// 0-1023, waves 4-7 keys 1024-2047 (same 128 q-rows). Fixed-max softmax
// makes partials combine linearly in the epilogue via LDS. 2 blocks/CU ->
// 4 waves/SIMD (vs 2), per-wave K-loop halves to 16 iters. Single Ps buffer
// per wave (same-wave LDS ordering makes the g0->g1 reuse WAR-safe).

typedef unsigned int u32;
typedef unsigned short u16;
typedef unsigned long long u64;

#define BH 32
#define Lseq 2048
#define Dh 64

typedef __attribute__((ext_vector_type(8))) short frag_ab;   // 8 bf16
typedef __attribute__((ext_vector_type(4))) float frag_cd;   // 4 fp32

__device__ __forceinline__ u16 f2bf(float f) {
    u32 u = __float_as_uint(f);
    u32 r = u + 0x7FFFu + ((u >> 16) & 1u);   // RNE
    return (u16)(r >> 16);
}

// ---- prep: K*0.125->bf16 | V->V^T bf16 | mask->u64 bitpack (key-major) ----
// (unchanged from round 6 — this round isolates the main-kernel change)
__global__ __launch_bounds__(256) void prep(
    const float* __restrict__ k, const float* __restrict__ v,
    const int* __restrict__ mask,
    u16* __restrict__ kb, u16* __restrict__ vtb, u64* __restrict__ bm)
{
    const int blk = blockIdx.x, tid = threadIdx.x;
    if (blk < 1024) {
        #pragma unroll
        for (int i = 0; i < 4; i++) {
            int idx = blk * 1024 + i * 256 + tid;
            float4 f = ((const float4*)k)[idx];
            ushort4 r;
            r.x = f2bf(f.x * 0.125f); r.y = f2bf(f.y * 0.125f);
            r.z = f2bf(f.z * 0.125f); r.w = f2bf(f.w * 0.125f);
            ((ushort4*)kb)[idx] = r;
        }
    } else if (blk < 2048) {
        __shared__ u16 T[64 * 72];
        int job = blk - 1024;
        int bh = job >> 5, kt = job & 31;
        #pragma unroll
        for (int i = 0; i < 4; i++) {
            int idx = tid + 256 * i;
            int key = idx >> 4, ds = idx & 15;
            float4 f = *(const float4*)(v + ((size_t)(bh * Lseq + kt * 64 + key)) * Dh + ds * 4);
            int d0 = ds * 4;
            T[(d0 + 0) * 72 + key] = f2bf(f.x);
            T[(d0 + 1) * 72 + key] = f2bf(f.y);
            T[(d0 + 2) * 72 + key] = f2bf(f.z);
            T[(d0 + 3) * 72 + key] = f2bf(f.w);
        }
        __syncthreads();
        #pragma unroll
        for (int i = 0; i < 4; i++) {
            int idx = tid + 256 * i;
            int d = idx >> 4, ks = idx & 15;
            *(uint2*)(vtb + ((size_t)(bh * Dh + d)) * Lseq + kt * 64 + ks * 4) =
                *(const uint2*)&T[d * 72 + ks * 4];
        }
    } else {
        int wv = (blk - 2048) * 4 + (tid >> 6);
        int lane = tid & 63;
        #pragma unroll
        for (int i = 0; i < 16; i++) {
            int widx = wv * 16 + i;
            int rowp = widx >> 5, kt = widx & 31;
            int val = mask[(size_t)rowp * Lseq + kt * 64 + lane];
            u64 bal = __ballot(val != 0);
            if (lane == 0) bm[(size_t)kt * 4096 + rowp] = bal;
        }
    }
}

// ------------- main: 512 threads, 2-way K-split, 32 rows/wave -------------
__global__ __launch_bounds__(512, 4)
void attn_mfma(const float* __restrict__ qg, const u16* __restrict__ kb,
               const u16* __restrict__ vtb, const u64* __restrict__ bm,
               float* __restrict__ outg)
{
    const int bh = blockIdx.y, b = bh >> 4;
    const int q0 = blockIdx.x * 128;
    const int tid = threadIdx.x;
    const int wave = tid >> 6, lane = tid & 63;
    const int half = wave >> 2, w2 = wave & 3;
    const int c = lane & 15, quad = lane >> 4;

    // LDS: [half]{K 9216B, V 9216B} = 36864B | Ps 8 x 2304B = 18432B -> 55296B
    // epilogue overlays Of (128x68 f32 = 34816B) + Lf (512B) on the K/V region
    __shared__ __align__(16) char smem[55296];
    u16* Ks = (u16*)(smem + half * 18432);
    u16* Vs = (u16*)(smem + half * 18432 + 9216);
    u16* Ps = (u16*)(smem + 36864 + wave * 2304);
    float* Of = (float*)smem;
    float* Lf = (float*)(smem + 34816);

    // ---- Q B-frags from fp32 global (0.125 scale lives in K) ----
    frag_ab qf[2][2];
    #pragma unroll
    for (int g = 0; g < 2; g++)
        #pragma unroll
        for (int ks = 0; ks < 2; ks++) {
            const float* p = qg + ((size_t)bh * Lseq + q0 + 32 * w2 + 16 * g + c) * Dh
                                + 32 * ks + 8 * quad;
            float4 f0 = *(const float4*)p;
            float4 f1 = *(const float4*)(p + 4);
            union { u32 w[4]; frag_ab f; } uq;
            uq.w[0] = (u32)f2bf(f0.x) | ((u32)f2bf(f0.y) << 16);
            uq.w[1] = (u32)f2bf(f0.z) | ((u32)f2bf(f0.w) << 16);
            uq.w[2] = (u32)f2bf(f1.x) | ((u32)f2bf(f1.y) << 16);
            uq.w[3] = (u32)f2bf(f1.z) | ((u32)f2bf(f1.w) << 16);
            qf[g][ks] = uq.f;
        }

    frag_cd o_acc[4][2];
    #pragma unroll
    for (int dt = 0; dt < 4; dt++)
        #pragma unroll
        for (int g = 0; g < 2; g++) o_acc[dt][g] = (frag_cd){0.f, 0.f, 0.f, 0.f};
    float l_run[2] = {0.f, 0.f};

    // staging: 256 lanes per half stage 512 uint4 (K) + 512 uint4 (V)
    const int sidx0 = tid & 255, sidx1 = sidx0 + 256;
    const int lds0 = (sidx0 >> 3) * 72 + (sidx0 & 7) * 8;
    const int lds1 = (sidx1 >> 3) * 72 + (sidx1 & 7) * 8;
    const int k0g = 1024 * half;                       // first key of this half
    const size_t kgbase = (size_t)bh * Lseq * Dh + (size_t)k0g * Dh;
    const size_t vg0 = ((size_t)(bh * Dh + (sidx0 >> 3))) * Lseq + k0g + (sidx0 & 7) * 8;
    const size_t vg1 = ((size_t)(bh * Dh + (sidx1 >> 3))) * Lseq + k0g + (sidx1 & 7) * 8;

    // ---- preload tile 0 of this half ----
    *(uint4*)&Ks[lds0] = *(const uint4*)(kb + kgbase + sidx0 * 8);
    *(uint4*)&Ks[lds1] = *(const uint4*)(kb + kgbase + sidx1 * 8);
    *(uint4*)&Vs[lds0] = *(const uint4*)(vtb + vg0);
    *(uint4*)&Vs[lds1] = *(const uint4*)(vtb + vg1);
    __syncthreads();

    for (int kt = 0; kt < 16; ++kt) {
        const int ktg = 16 * half + kt;
        const bool has_next = (kt + 1) < 16;

        u64 mw[2];
        #pragma unroll
        for (int g = 0; g < 2; g++)
            mw[g] = bm[(size_t)ktg * 4096 + b * 2048 + q0 + 32 * w2 + 16 * g + c];

        uint4 kr0, kr1, vr0, vr1;
        if (has_next) {
            size_t kofs = kgbase + (size_t)(kt + 1) * 64 * Dh;
            kr0 = *(const uint4*)(kb + kofs + sidx0 * 8);
            kr1 = *(const uint4*)(kb + kofs + sidx1 * 8);
            vr0 = *(const uint4*)(vtb + vg0 + (kt + 1) * 64);
            vr1 = *(const uint4*)(vtb + vg1 + (kt + 1) * 64);
        }

        u32 wlo[2], whi[2];
        #pragma unroll
        for (int g = 0; g < 2; g++) {
            u64 sh = mw[g] >> (4 * quad);
            wlo[g] = (u32)sh; whi[g] = (u32)(sh >> 32);
        }

        // ---- S^T = K·Q^T with C-init = bias/mask (-12 live, -1e9 masked) ----
        frag_cd s_acc[2][4];
        #pragma unroll
        for (int t = 0; t < 4; t++) {
            frag_ab kf0 = *(const frag_ab*)&Ks[(16 * t + c) * 72 + 8 * quad];
            frag_ab kf1 = *(const frag_ab*)&Ks[(16 * t + c) * 72 + 32 + 8 * quad];
            #pragma unroll
            for (int g = 0; g < 2; g++) {
                u32 wb = (t < 2) ? wlo[g] : whi[g];
                const int base = 16 * (t & 1);
                frag_cd ci;
                #pragma unroll
                for (int r = 0; r < 4; r++)
                    ci[r] = (wb & (1u << (base + r))) ? -12.0f : -1e9f;
                ci = __builtin_amdgcn_mfma_f32_16x16x32_bf16(kf0, qf[g][0], ci, 0, 0, 0);
                s_acc[g][t] = __builtin_amdgcn_mfma_f32_16x16x32_bf16(kf1, qf[g][1], ci, 0, 0, 0);
            }
        }

        // ---- fixed-max softmax + P^T->B-frag (single Ps buffer, WAR-safe) ----
        frag_ab pf[2][2];
        #pragma unroll
        for (int g = 0; g < 2; g++) {
            float lsum = 0.f;
            #pragma unroll
            for (int t = 0; t < 4; t++)
                #pragma unroll
                for (int r = 0; r < 4; r++) {
                    float pv = __expf(s_acc[g][t][r]);
                    s_acc[g][t][r] = pv;
                    lsum += pv;
                }
            l_run[g] += lsum;

            #pragma unroll
            for (int t = 0; t < 4; t++) {
                u32 p0 = __builtin_amdgcn_perm(__float_as_uint(s_acc[g][t][1]),
                                               __float_as_uint(s_acc[g][t][0]), 0x07060302u);
                u32 p1 = __builtin_amdgcn_perm(__float_as_uint(s_acc[g][t][3]),
                                               __float_as_uint(s_acc[g][t][2]), 0x07060302u);
                *(uint2*)&Ps[c * 72 + 16 * t + 4 * quad] = make_uint2(p0, p1);
            }
            pf[g][0] = *(const frag_ab*)&Ps[c * 72 + 8 * quad];
            pf[g][1] = *(const frag_ab*)&Ps[c * 72 + 32 + 8 * quad];
        }

        // ---- O^T += V^T · P^T ----
        #pragma unroll
        for (int dt = 0; dt < 4; dt++) {
            frag_ab vf0 = *(const frag_ab*)&Vs[(16 * dt + c) * 72 + 8 * quad];
            frag_ab vf1 = *(const frag_ab*)&Vs[(16 * dt + c) * 72 + 32 + 8 * quad];
            #pragma unroll
            for (int g = 0; g < 2; g++) {
                o_acc[dt][g] = __builtin_amdgcn_mfma_f32_16x16x32_bf16(vf0, pf[g][0], o_acc[dt][g], 0, 0, 0);
                o_acc[dt][g] = __builtin_amdgcn_mfma_f32_16x16x32_bf16(vf1, pf[g][1], o_acc[dt][g], 0, 0, 0);
            }
        }

        if (has_next) {
            __syncthreads();
            *(uint4*)&Ks[lds0] = kr0;  *(uint4*)&Ks[lds1] = kr1;
            *(uint4*)&Vs[lds0] = vr0;  *(uint4*)&Vs[lds1] = vr1;
            __syncthreads();
        }
    }

    // ---- epilogue: combine halves linearly (fixed max), normalize, store ----
    __syncthreads();                      // all K/V reads done; region reusable
    float lq[2];
    #pragma unroll
    for (int g = 0; g < 2; g++) {
        float l = l_run[g];
        l += __shfl_xor(l, 16);
        l += __shfl_xor(l, 32);
        lq[g] = l;
    }
    if (half == 1) {
        #pragma unroll
        for (int g = 0; g < 2; g++) {
            int rl = 32 * w2 + 16 * g + c;
            #pragma unroll
            for (int dt = 0; dt < 4; dt++)
                *(float4*)&Of[rl * 68 + 16 * dt + 4 * quad] =
                    make_float4(o_acc[dt][g][0], o_acc[dt][g][1],
                                o_acc[dt][g][2], o_acc[dt][g][3]);
            if (quad == 0) Lf[rl] = lq[g];
        }
    }
    __syncthreads();
    if (half == 0) {
        #pragma unroll
        for (int g = 0; g < 2; g++) {
            int rl = 32 * w2 + 16 * g + c;
            const float inv = 1.0f / (lq[g] + Lf[rl]);
            float* orow = outg + ((size_t)bh * Lseq + q0 + rl) * Dh;
            #pragma unroll
            for (int dt = 0; dt < 4; dt++) {
                float4 t = *(const float4*)&Of[rl * 68 + 16 * dt + 4 * quad];
                *(float4*)(orow + 16 * dt + 4 * quad) =
                    make_float4((o_acc[dt][g][0] + t.x) * inv,
                                (o_acc[dt][g][1] + t.y) * inv,
                                (o_acc[dt][g][2] + t.z) * inv,
                                (o_acc[dt][g][3] + t.w) * inv);
            }
        }
    }
}

extern "C" void kernel_launch(void* const* d_in, const int* in_sizes, int n_in,
                              void* d_out, int out_size, void* d_ws, size_t ws_size,
                              hipStream_t stream) {
    const float* q    = (const float*)d_in[0];
    const float* k    = (const float*)d_in[1];
    const float* v    = (const float*)d_in[2];
    const int*   mask = (const int*)d_in[3];
    float* out = (float*)d_out;

    char* ws = (char*)d_ws;
    u16* kb  = (u16*)(ws);                      // 8.39 MB
    u16* vtb = (u16*)(ws + 8388608);            // 8.39 MB
    u64* bmp = (u64*)(ws + 16777216);           // 1.05 MB

    hipLaunchKernelGGL(prep, dim3(4096), dim3(256), 0, stream, k, v, mask, kb, vtb, bmp);
    hipLaunchKernelGGL(attn_mfma, dim3(Lseq / 128, BH), dim3(512), 0, stream,
                       q, kb, vtb, bmp, out);
}